// Round 6
// baseline (392.737 us; speedup 1.0000x reference)
//
#include <hip/hip_runtime.h>

// NNLS via normal equations + FISTA.
// Phase 1: M = U^T U, U = [X | y | 1] (2e6 x 37). ROUND 5: barrier-free gram
//          (r4) + DEPTH-2 register prefetch. Each wave stages its OWN 16-row
//          band into its OWN LDS region (X [16][36] pad-36 + y [16][4]);
//          intra-wave DS ordering needs no barriers. Two register sets A/B
//          alternate via a 2-unrolled loop, so a band's global loads are
//          issued TWO compute phases (~1500 cyc) before their ds_write --
//          covers the ~900 cyc HBM-miss latency that depth-1 (r1/r4) only
//          marginally hid. +9 VGPR (~119, still 4 waves/SIMD, 4 blocks/CU).
//          Zero __syncthreads in the main loop. Grid 1024 = 4 blocks/CU.
// Phase 1b: atomic-free coalesced reduction of per-block partials (transposed
//           layout) into the 40x40 Gram, one block per entry.
// Phase 2: power iteration (8) + FISTA (32); LDS-broadcast matvec, one wave
//          per output column. kappa(G)~1.016 -> fp32-converged well before 32.
//
// NOTE (rounds 1-4): ~306 us of ~392 us total is the harness's 2x 1GB
// workspace poison fill inside the timed region (untouchable). Kernel portion
// ~86 us: gram ~60-68 us vs 46 us HBM floor; reduce+solve+launch ~18 us.
// r2/r3 DMA staging: -12 us regression (machinery overhead). r4 barrier-free
// == r1. Depth-1 prefetch window was the untouched knob.

#define NROWS 2000000
#define TR 64                 // tile rows
#define NT (NROWS / TR)       // 31250 tiles, exact
#define GB 1024               // gram blocks (4 blocks/CU)
#define PITERS 8
#define QPITERS 32

#define BAND 16               // rows per wave
#define XPAD 36               // padded X row stride (additive (r+c)&7 spread)
#define YOFFW (BAND * XPAD)   // 576: y region within wave buffer
#define WBUF (YOFFW + BAND * 4)  // 640 floats per wave buffer

// u-row layout: [x0..x31 | y0..y3 | 1 | 0 0 0] = cols 0..39
__global__ __launch_bounds__(256) void gram_kernel(const float* __restrict__ X,
                                                   const float* __restrict__ Yg,
                                                   float* __restrict__ Pw) {
  __shared__ float sm[3840];  // 4*WBUF=2560 live in loop; 3840 epilogue overlay
  const int tid  = threadIdx.x;
  const int lane = tid & 63;
  const int wv   = tid >> 6;
  const int team = lane >> 4;   // 4 teams of 16 lanes
  const int p    = lane & 15;   // patch id; 15 active

  // patch p -> (PI,PJ) in upper triangle of the 5x5 grid of 8x8 col-blocks
  int pp = (p < 15) ? p : 0;
  int PI = 0, rem = pp;
  while (rem >= 5 - PI) { rem -= 5 - PI; ++PI; }
  const int PJ = PI + rem;
  const int PI2 = PI * 2, PJ2 = PJ * 2;
  const bool aX = (PI < 4);     // a-fragment from X band (else y/ones)
  const bool bX = (PJ < 4);

  float* myb = &sm[wv * WBUF];  // this wave's private buffer

  // staging: lane covers band rows srow and srow+8, float4 chunk sch
  const int srow = lane >> 3;   // 0..7
  const int sch  = lane & 7;
  const int w0 = srow * XPAD + sch * 4;
  const int w1 = (srow + 8) * XPAD + sch * 4;
  const int wy = YOFFW + lane;  // 1 float/lane covers 16x4 y band
  const float4* X4 = (const float4*)X;

  // per-rs read offsets (band-relative float indices), compile-time indexed
  int ra0[4], ra1[4], rb0[4], rb1[4];
#pragma unroll
  for (int rs = 0; rs < 4; ++rs) {
    const int rloc = team + rs * 4;   // band row 0..15
    ra0[rs] = aX ? rloc * XPAD + (PI2    ) * 4 : YOFFW + rloc * 4;
    ra1[rs] = aX ? rloc * XPAD + (PI2 | 1) * 4 : YOFFW + rloc * 4;
    rb0[rs] = bX ? rloc * XPAD + (PJ2    ) * 4 : YOFFW + rloc * 4;
    rb1[rs] = bX ? rloc * XPAD + (PJ2 | 1) * 4 : YOFFW + rloc * 4;
  }

  float acc[8][8];
#pragma unroll
  for (int a = 0; a < 8; ++a)
#pragma unroll
    for (int b = 0; b < 8; ++b) acc[a][b] = 0.f;

  const float4 onesfrag = make_float4(1.f, 0.f, 0.f, 0.f);

#define LOADBAND(t_, V0, V1, YV)                              \
  {                                                           \
    const size_t gr_ = (size_t)(t_)*TR + wv * BAND;           \
    V0 = X4[(gr_ + srow) * 8 + sch];                          \
    V1 = X4[(gr_ + srow + 8) * 8 + sch];                      \
    YV = Yg[(gr_ + (lane >> 2)) * 4 + (lane & 3)];            \
  }

  // prologue: depth-2 — band(tile) in set A, band(tile+GB) in set B
  // (tile <= 1023, tile+GB <= 2047 < NT always)
  int tile = blockIdx.x;
  float4 v0a, v1a, v0b, v1b; float yva, yvb;
  LOADBAND(tile, v0a, v1a, yva);
  LOADBAND(tile + GB, v0b, v1b, yvb);

  while (tile < NT) {
    // --- step k: consume set A, refill A with band(tile+2GB) ---
    *(float4*)&myb[w0] = v0a;
    *(float4*)&myb[w1] = v1a;
    myb[wy] = yva;
    if (tile + 2 * GB < NT) LOADBAND(tile + 2 * GB, v0a, v1a, yva);
#pragma unroll
    for (int rs = 0; rs < 4; ++rs) {
      float4 a0 = *(const float4*)&myb[ra0[rs]];
      float4 a1 = *(const float4*)&myb[ra1[rs]];
      float4 b0 = *(const float4*)&myb[rb0[rs]];
      float4 b1 = *(const float4*)&myb[rb1[rs]];
      if (!aX) a1 = onesfrag;
      if (!bX) b1 = onesfrag;
      float av[8] = {a0.x, a0.y, a0.z, a0.w, a1.x, a1.y, a1.z, a1.w};
      float bv[8] = {b0.x, b0.y, b0.z, b0.w, b1.x, b1.y, b1.z, b1.w};
#pragma unroll
      for (int a = 0; a < 8; ++a)
#pragma unroll
        for (int b = 0; b < 8; ++b) acc[a][b] = fmaf(av[a], bv[b], acc[a][b]);
    }
    tile += GB;
    if (tile >= NT) break;

    // --- step k+1: consume set B, refill B with band(tile+2GB) ---
    *(float4*)&myb[w0] = v0b;
    *(float4*)&myb[w1] = v1b;
    myb[wy] = yvb;
    if (tile + 2 * GB < NT) LOADBAND(tile + 2 * GB, v0b, v1b, yvb);
#pragma unroll
    for (int rs = 0; rs < 4; ++rs) {
      float4 a0 = *(const float4*)&myb[ra0[rs]];
      float4 a1 = *(const float4*)&myb[ra1[rs]];
      float4 b0 = *(const float4*)&myb[rb0[rs]];
      float4 b1 = *(const float4*)&myb[rb1[rs]];
      if (!aX) a1 = onesfrag;
      if (!bX) b1 = onesfrag;
      float av[8] = {a0.x, a0.y, a0.z, a0.w, a1.x, a1.y, a1.z, a1.w};
      float bv[8] = {b0.x, b0.y, b0.z, b0.w, b1.x, b1.y, b1.z, b1.w};
#pragma unroll
      for (int a = 0; a < 8; ++a)
#pragma unroll
        for (int b = 0; b < 8; ++b) acc[a][b] = fmaf(av[a], bv[b], acc[a][b]);
    }
    tile += GB;
  }

  // cross-team reduce (lane bits 4,5), then transposed partial store:
  // Pw[e*GB + block] -> reduce_kernel reads coalesced
#pragma unroll
  for (int a = 0; a < 8; ++a)
#pragma unroll
    for (int b = 0; b < 8; ++b) {
      float v = acc[a][b];
      v += __shfl_xor(v, 16);
      v += __shfl_xor(v, 32);
      acc[a][b] = v;
    }
  __syncthreads();  // all waves done with private buffers -> overlay reuse
  if (p < 15 && team == 0) {
#pragma unroll
    for (int a = 0; a < 8; ++a)
#pragma unroll
      for (int b = 0; b < 8; ++b)
        sm[wv * 960 + p * 64 + a * 8 + b] = acc[a][b];
  }
  __syncthreads();
  for (int e = tid; e < 960; e += 256)
    Pw[(size_t)e * GB + blockIdx.x] = sm[e] + sm[e + 960] + sm[e + 1920] + sm[e + 2880];
}

// One block per Gram entry; coalesced fold of GB partials; scatter into 40x40.
__global__ __launch_bounds__(256) void reduce_kernel(const float* __restrict__ Pw,
                                                     float* __restrict__ Mw) {
  __shared__ float red[4];
  const int t   = blockIdx.x;       // entry 0..959
  const int tid = threadIdx.x;
  float s = 0.f;
#pragma unroll
  for (int k = 0; k < GB / 256; ++k) s += Pw[(size_t)t * GB + k * 256 + tid];
#pragma unroll
  for (int off = 32; off; off >>= 1) s += __shfl_xor(s, off);
  if ((tid & 63) == 0) red[tid >> 6] = s;
  __syncthreads();
  if (tid == 0) {
    float sum = red[0] + red[1] + red[2] + red[3];
    int pe = t >> 6, idx = t & 63;
    int bi = 0, r2 = pe;
    while (r2 >= 5 - bi) { r2 -= 5 - bi; ++bi; }
    const int bj = bi + r2;
    Mw[(bi * 8 + (idx >> 3)) * 40 + (bj * 8 + (idx & 7))] = sum;
  }
}

// dot of 36-float register row with 36-float LDS vector (uniform addr = broadcast)
__device__ __forceinline__ float dot36(const float* __restrict__ Gr, const float4* __restrict__ y4) {
  float g0 = 0.f, g1 = 0.f, g2 = 0.f, g3 = 0.f;
#pragma unroll
  for (int c = 0; c < 9; ++c) {
    float4 y = y4[c];
    g0 = fmaf(Gr[c * 4 + 0], y.x, g0);
    g1 = fmaf(Gr[c * 4 + 1], y.y, g1);
    g2 = fmaf(Gr[c * 4 + 2], y.z, g2);
    g3 = fmaf(Gr[c * 4 + 3], y.w, g3);
  }
  return (g0 + g1) + (g2 + g3);
}

__device__ __forceinline__ float wave_sum(float x) {
#pragma unroll
  for (int off = 32; off; off >>= 1) x += __shfl_xor(x, off);
  return x;
}

// A-col a in [0,33): U(a) = a<32 ? a : 36. c columns = u-cols 32..35.
// M holds upper 8x8 blocks only: mirror via (Ui>>3) vs (Uk>>3).
__global__ __launch_bounds__(256) void solve_kernel(const float* __restrict__ Mw,
                                                    float* __restrict__ out) {
  __shared__ float4 Yb4[2][4][9];
  const int tid  = threadIdx.x;
  const int lane = tid & 63;
  const int col  = tid >> 6;       // one wave per output column
  const bool act = lane < 33;
  const int i  = act ? lane : 0;
  const int Ui = (i < 32) ? i : 36;

  float Gr[36];
#pragma unroll
  for (int k = 0; k < 33; ++k) {
    const int Uk = (k < 32) ? k : 36;
    Gr[k] = ((Ui >> 3) <= (Uk >> 3)) ? Mw[Ui * 40 + Uk] : Mw[Uk * 40 + Ui];
  }
  Gr[33] = Gr[34] = Gr[35] = 0.f;
  const float ci = Mw[Ui * 40 + 32 + col];

  if (lane < 9) {
    Yb4[0][col][lane] = make_float4(0.f, 0.f, 0.f, 0.f);
    Yb4[1][col][lane] = make_float4(0.f, 0.f, 0.f, 0.f);
  }
  __syncthreads();
  float v = rsqrtf(33.f);
  if (act) ((float*)&Yb4[0][col][0])[i] = v;
  __syncthreads();

  // power iteration for step; Rayleigh quotient <= lambda_max, so step >= 1/L;
  // any step in (0, 2/L) converges to the same QP fixed point (kappa ~ 1.016)
  for (int it = 0; it < PITERS; ++it) {
    const int rb = it & 1;
    float w = dot36(Gr, &Yb4[rb][col][0]);
    float x = wave_sum(act ? w * w : 0.f);
    float vn = w * rsqrtf(x);
    if (act) ((float*)&Yb4[rb ^ 1][col][0])[i] = vn;
    v = vn;
    __syncthreads();
  }
  {
    const int rb = PITERS & 1;
    float w = dot36(Gr, &Yb4[rb][col][0]);
    v = wave_sum(act ? v * w : 0.f);  // v^T G v
  }
  const float step = 1.f / v;

  __syncthreads();
  if (act) ((float*)&Yb4[0][col][0])[i] = 0.f;
  __syncthreads();

  float Z = 0.f, Yv = 0.f, t = 1.f;
  for (int it = 0; it < QPITERS; ++it) {
    const int rb = it & 1;
    float g = dot36(Gr, &Yb4[rb][col][0]);
    float zn = Yv - step * (g - ci);
    if (lane < 32) zn = fmaxf(zn, 0.f);  // W rows clamped; bias row free
    float tn = 0.5f * (1.f + sqrtf(fmaf(4.f * t, t, 1.f)));
    float beta = (t - 1.f) / tn;
    float yn = fmaf(beta, zn - Z, zn);
    if (act) ((float*)&Yb4[rb ^ 1][col][0])[i] = yn;
    Z = zn; Yv = yn; t = tn;
    __syncthreads();
  }
  if (lane < 32) out[lane * 4 + col] = Z;  // W is [32,4] row-major
}

extern "C" void kernel_launch(void* const* d_in, const int* in_sizes, int n_in,
                              void* d_out, int out_size, void* d_ws, size_t ws_size,
                              hipStream_t stream) {
  const float* X  = (const float*)d_in[0];
  const float* Yg = (const float*)d_in[1];
  float* Pw  = (float*)d_ws;                 // 960*GB floats of partials (transposed)
  float* Mw  = Pw + (size_t)960 * GB;        // 40x40 Gram (upper blocks)
  float* out = (float*)d_out;

  hipLaunchKernelGGL(gram_kernel,   dim3(GB),  dim3(256), 0, stream, X, Yg, Pw);
  hipLaunchKernelGGL(reduce_kernel, dim3(960), dim3(256), 0, stream, Pw, Mw);
  hipLaunchKernelGGL(solve_kernel,  dim3(1),   dim3(256), 0, stream, Mw, out);
}

// Round 8
// 392.677 us; speedup vs baseline: 1.0002x; 1.0002x over previous
//
#include <hip/hip_runtime.h>
#include <hip/hip_cooperative_groups.h>

namespace cg = cooperative_groups;

// NNLS via normal equations + FISTA.
// ROUND 7: ONE cooperative kernel fusing gram -> reduce -> solve (kills 2
// dependent-dispatch gaps + small-kernel launch overhead). Phase bodies are
// the r5 code verbatim (bit-identical arithmetic -> absmax 0.0 preserved):
//   A: barrier-free gram, per-wave private LDS bands, depth-2 reg prefetch.
//   B: blocks 0..959 fold 1024 partials/entry into the 40x40 Gram.
//   C: block 0: power iteration (8) + FISTA (32).
// Cross-XCD visibility inside the fused kernel: __threadfence() (agent fence
// = L2 wb/inv on gfx950) around each grid.sync().
// SAFETY: host queries occupancy; if 4 blocks/CU not guaranteed (VGPR creep)
// or cooperative launch errors, falls back to the proven 3-kernel path.
//
// Budget (r1-r6 counters): ~306 us of ~392 us is the harness's 2x 1GB
// workspace poison fill (untouchable). Non-fill ~86 us: gram ~50-65 vs 46
// HBM floor (3 staging variants all equal -> plateau), reduce ~4, solve
// ~8-13, plus 3 dispatch gaps. This round attacks the gaps.

#define NROWS 2000000
#define TR 64                 // tile rows
#define NT (NROWS / TR)       // 31250 tiles, exact
#define GB 1024               // gram blocks (4 blocks/CU)
#define PITERS 8
#define QPITERS 32

#define BAND 16               // rows per wave
#define XPAD 36               // padded X row stride (additive (r+c)&7 spread)
#define YOFFW (BAND * XPAD)   // 576: y region within wave buffer
#define WBUF (YOFFW + BAND * 4)  // 640 floats per wave buffer

// ---------------- phase A: gram ----------------
__device__ __forceinline__ void gram_body(const float* __restrict__ X,
                                          const float* __restrict__ Yg,
                                          float* __restrict__ Pw,
                                          float* sm) {
  const int tid  = threadIdx.x;
  const int lane = tid & 63;
  const int wv   = tid >> 6;
  const int team = lane >> 4;   // 4 teams of 16 lanes
  const int p    = lane & 15;   // patch id; 15 active

  // patch p -> (PI,PJ) in upper triangle of the 5x5 grid of 8x8 col-blocks
  int pp = (p < 15) ? p : 0;
  int PI = 0, rem = pp;
  while (rem >= 5 - PI) { rem -= 5 - PI; ++PI; }
  const int PJ = PI + rem;
  const int PI2 = PI * 2, PJ2 = PJ * 2;
  const bool aX = (PI < 4);     // a-fragment from X band (else y/ones)
  const bool bX = (PJ < 4);

  float* myb = &sm[wv * WBUF];  // this wave's private buffer

  // staging: lane covers band rows srow and srow+8, float4 chunk sch
  const int srow = lane >> 3;   // 0..7
  const int sch  = lane & 7;
  const int w0 = srow * XPAD + sch * 4;
  const int w1 = (srow + 8) * XPAD + sch * 4;
  const int wy = YOFFW + lane;  // 1 float/lane covers 16x4 y band
  const float4* X4 = (const float4*)X;

  // per-rs read offsets (band-relative float indices), compile-time indexed
  int ra0[4], ra1[4], rb0[4], rb1[4];
#pragma unroll
  for (int rs = 0; rs < 4; ++rs) {
    const int rloc = team + rs * 4;   // band row 0..15
    ra0[rs] = aX ? rloc * XPAD + (PI2    ) * 4 : YOFFW + rloc * 4;
    ra1[rs] = aX ? rloc * XPAD + (PI2 | 1) * 4 : YOFFW + rloc * 4;
    rb0[rs] = bX ? rloc * XPAD + (PJ2    ) * 4 : YOFFW + rloc * 4;
    rb1[rs] = bX ? rloc * XPAD + (PJ2 | 1) * 4 : YOFFW + rloc * 4;
  }

  float acc[8][8];
#pragma unroll
  for (int a = 0; a < 8; ++a)
#pragma unroll
    for (int b = 0; b < 8; ++b) acc[a][b] = 0.f;

  const float4 onesfrag = make_float4(1.f, 0.f, 0.f, 0.f);

#define LOADBAND(t_, V0, V1, YV)                              \
  {                                                           \
    const size_t gr_ = (size_t)(t_)*TR + wv * BAND;           \
    V0 = X4[(gr_ + srow) * 8 + sch];                          \
    V1 = X4[(gr_ + srow + 8) * 8 + sch];                      \
    YV = Yg[(gr_ + (lane >> 2)) * 4 + (lane & 3)];            \
  }

  // prologue: depth-2 — band(tile) in set A, band(tile+GB) in set B
  int tile = blockIdx.x;
  float4 v0a, v1a, v0b, v1b; float yva, yvb;
  LOADBAND(tile, v0a, v1a, yva);
  LOADBAND(tile + GB, v0b, v1b, yvb);

  while (tile < NT) {
    // --- step k: consume set A, refill A with band(tile+2GB) ---
    *(float4*)&myb[w0] = v0a;
    *(float4*)&myb[w1] = v1a;
    myb[wy] = yva;
    if (tile + 2 * GB < NT) LOADBAND(tile + 2 * GB, v0a, v1a, yva);
#pragma unroll
    for (int rs = 0; rs < 4; ++rs) {
      float4 a0 = *(const float4*)&myb[ra0[rs]];
      float4 a1 = *(const float4*)&myb[ra1[rs]];
      float4 b0 = *(const float4*)&myb[rb0[rs]];
      float4 b1 = *(const float4*)&myb[rb1[rs]];
      if (!aX) a1 = onesfrag;
      if (!bX) b1 = onesfrag;
      float av[8] = {a0.x, a0.y, a0.z, a0.w, a1.x, a1.y, a1.z, a1.w};
      float bv[8] = {b0.x, b0.y, b0.z, b0.w, b1.x, b1.y, b1.z, b1.w};
#pragma unroll
      for (int a = 0; a < 8; ++a)
#pragma unroll
        for (int b = 0; b < 8; ++b) acc[a][b] = fmaf(av[a], bv[b], acc[a][b]);
    }
    tile += GB;
    if (tile >= NT) break;

    // --- step k+1: consume set B, refill B with band(tile+2GB) ---
    *(float4*)&myb[w0] = v0b;
    *(float4*)&myb[w1] = v1b;
    myb[wy] = yvb;
    if (tile + 2 * GB < NT) LOADBAND(tile + 2 * GB, v0b, v1b, yvb);
#pragma unroll
    for (int rs = 0; rs < 4; ++rs) {
      float4 a0 = *(const float4*)&myb[ra0[rs]];
      float4 a1 = *(const float4*)&myb[ra1[rs]];
      float4 b0 = *(const float4*)&myb[rb0[rs]];
      float4 b1 = *(const float4*)&myb[rb1[rs]];
      if (!aX) a1 = onesfrag;
      if (!bX) b1 = onesfrag;
      float av[8] = {a0.x, a0.y, a0.z, a0.w, a1.x, a1.y, a1.z, a1.w};
      float bv[8] = {b0.x, b0.y, b0.z, b0.w, b1.x, b1.y, b1.z, b1.w};
#pragma unroll
      for (int a = 0; a < 8; ++a)
#pragma unroll
        for (int b = 0; b < 8; ++b) acc[a][b] = fmaf(av[a], bv[b], acc[a][b]);
    }
    tile += GB;
  }

  // cross-team reduce (lane bits 4,5), then transposed partial store:
  // Pw[e*GB + block] -> reduce phase reads coalesced
#pragma unroll
  for (int a = 0; a < 8; ++a)
#pragma unroll
    for (int b = 0; b < 8; ++b) {
      float v = acc[a][b];
      v += __shfl_xor(v, 16);
      v += __shfl_xor(v, 32);
      acc[a][b] = v;
    }
  __syncthreads();  // all waves done with private buffers -> overlay reuse
  if (p < 15 && team == 0) {
#pragma unroll
    for (int a = 0; a < 8; ++a)
#pragma unroll
      for (int b = 0; b < 8; ++b)
        sm[wv * 960 + p * 64 + a * 8 + b] = acc[a][b];
  }
  __syncthreads();
  for (int e = tid; e < 960; e += 256)
    Pw[(size_t)e * GB + blockIdx.x] = sm[e] + sm[e + 960] + sm[e + 1920] + sm[e + 2880];
}

// ---------------- phase B: reduce one Gram entry ----------------
__device__ __forceinline__ void reduce_body(const float* __restrict__ Pw,
                                            float* __restrict__ Mw,
                                            int t, float* red) {
  const int tid = threadIdx.x;
  float s = 0.f;
#pragma unroll
  for (int k = 0; k < GB / 256; ++k) s += Pw[(size_t)t * GB + k * 256 + tid];
#pragma unroll
  for (int off = 32; off; off >>= 1) s += __shfl_xor(s, off);
  if ((tid & 63) == 0) red[tid >> 6] = s;
  __syncthreads();
  if (tid == 0) {
    float sum = red[0] + red[1] + red[2] + red[3];
    int pe = t >> 6, idx = t & 63;
    int bi = 0, r2 = pe;
    while (r2 >= 5 - bi) { r2 -= 5 - bi; ++bi; }
    const int bj = bi + r2;
    Mw[(bi * 8 + (idx >> 3)) * 40 + (bj * 8 + (idx & 7))] = sum;
  }
}

// dot of 36-float register row with 36-float LDS vector (uniform addr = broadcast)
__device__ __forceinline__ float dot36(const float* __restrict__ Gr, const float4* __restrict__ y4) {
  float g0 = 0.f, g1 = 0.f, g2 = 0.f, g3 = 0.f;
#pragma unroll
  for (int c = 0; c < 9; ++c) {
    float4 y = y4[c];
    g0 = fmaf(Gr[c * 4 + 0], y.x, g0);
    g1 = fmaf(Gr[c * 4 + 1], y.y, g1);
    g2 = fmaf(Gr[c * 4 + 2], y.z, g2);
    g3 = fmaf(Gr[c * 4 + 3], y.w, g3);
  }
  return (g0 + g1) + (g2 + g3);
}

__device__ __forceinline__ float wave_sum(float x) {
#pragma unroll
  for (int off = 32; off; off >>= 1) x += __shfl_xor(x, off);
  return x;
}

// ---------------- phase C: solve ----------------
// A-col a in [0,33): U(a) = a<32 ? a : 36. c columns = u-cols 32..35.
// M holds upper 8x8 blocks only: mirror via (Ui>>3) vs (Uk>>3).
__device__ __forceinline__ void solve_body(const float* __restrict__ Mw,
                                           float* __restrict__ out,
                                           float* smem) {
  float4* Yb = (float4*)smem;      // [2][4][9] -> index rb*36 + col*9 + c
  const int tid  = threadIdx.x;
  const int lane = tid & 63;
  const int col  = tid >> 6;       // one wave per output column
  const bool act = lane < 33;
  const int i  = act ? lane : 0;
  const int Ui = (i < 32) ? i : 36;

  float Gr[36];
#pragma unroll
  for (int k = 0; k < 33; ++k) {
    const int Uk = (k < 32) ? k : 36;
    Gr[k] = ((Ui >> 3) <= (Uk >> 3)) ? Mw[Ui * 40 + Uk] : Mw[Uk * 40 + Ui];
  }
  Gr[33] = Gr[34] = Gr[35] = 0.f;
  const float ci = Mw[Ui * 40 + 32 + col];

  if (lane < 9) {
    Yb[0 * 36 + col * 9 + lane] = make_float4(0.f, 0.f, 0.f, 0.f);
    Yb[1 * 36 + col * 9 + lane] = make_float4(0.f, 0.f, 0.f, 0.f);
  }
  __syncthreads();
  float v = rsqrtf(33.f);
  if (act) ((float*)&Yb[0 * 36 + col * 9])[i] = v;
  __syncthreads();

  // power iteration for step; Rayleigh quotient <= lambda_max, so step >= 1/L;
  // any step in (0, 2/L) converges to the same QP fixed point (kappa ~ 1.016)
  for (int it = 0; it < PITERS; ++it) {
    const int rb = it & 1;
    float w = dot36(Gr, &Yb[rb * 36 + col * 9]);
    float x = wave_sum(act ? w * w : 0.f);
    float vn = w * rsqrtf(x);
    if (act) ((float*)&Yb[(rb ^ 1) * 36 + col * 9])[i] = vn;
    v = vn;
    __syncthreads();
  }
  {
    const int rb = PITERS & 1;
    float w = dot36(Gr, &Yb[rb * 36 + col * 9]);
    v = wave_sum(act ? v * w : 0.f);  // v^T G v
  }
  const float step = 1.f / v;

  __syncthreads();
  if (act) ((float*)&Yb[0 * 36 + col * 9])[i] = 0.f;
  __syncthreads();

  float Z = 0.f, Yv = 0.f, t = 1.f;
  for (int it = 0; it < QPITERS; ++it) {
    const int rb = it & 1;
    float g = dot36(Gr, &Yb[rb * 36 + col * 9]);
    float zn = Yv - step * (g - ci);
    if (lane < 32) zn = fmaxf(zn, 0.f);  // W rows clamped; bias row free
    float tn = 0.5f * (1.f + sqrtf(fmaf(4.f * t, t, 1.f)));
    float beta = (t - 1.f) / tn;
    float yn = fmaf(beta, zn - Z, zn);
    if (act) ((float*)&Yb[(rb ^ 1) * 36 + col * 9])[i] = yn;
    Z = zn; Yv = yn; t = tn;
    __syncthreads();
  }
  if (lane < 32) out[lane * 4 + col] = Z;  // W is [32,4] row-major
}

// ---------------- fused cooperative kernel ----------------
__global__ __launch_bounds__(256) void fused_kernel(const float* __restrict__ X,
                                                    const float* __restrict__ Yg,
                                                    float* __restrict__ Pw,
                                                    float* __restrict__ Mw,
                                                    float* __restrict__ out) {
  __shared__ float sm[3840];
  gram_body(X, Yg, Pw, sm);

  __threadfence();             // release partials (L2 writeback, agent scope)
  cg::this_grid().sync();
  __threadfence();             // acquire (invalidate stale L2 lines)

  if (blockIdx.x < 960) reduce_body(Pw, Mw, blockIdx.x, sm);

  __threadfence();
  cg::this_grid().sync();
  __threadfence();

  if (blockIdx.x == 0) solve_body(Mw, out, sm);
}

// ---------------- fallback standalone kernels (proven 3-launch path) -------
__global__ __launch_bounds__(256) void gram_kernel(const float* __restrict__ X,
                                                   const float* __restrict__ Yg,
                                                   float* __restrict__ Pw) {
  __shared__ float sm[3840];
  gram_body(X, Yg, Pw, sm);
}

__global__ __launch_bounds__(256) void reduce_kernel(const float* __restrict__ Pw,
                                                     float* __restrict__ Mw) {
  __shared__ float red[4];
  reduce_body(Pw, Mw, blockIdx.x, red);
}

__global__ __launch_bounds__(256) void solve_kernel(const float* __restrict__ Mw,
                                                    float* __restrict__ out) {
  __shared__ float smem[288];
  solve_body(Mw, out, smem);
}

extern "C" void kernel_launch(void* const* d_in, const int* in_sizes, int n_in,
                              void* d_out, int out_size, void* d_ws, size_t ws_size,
                              hipStream_t stream) {
  const float* X  = (const float*)d_in[0];
  const float* Yg = (const float*)d_in[1];
  float* Pw  = (float*)d_ws;                 // 960*GB floats of partials (transposed)
  float* Mw  = Pw + (size_t)960 * GB;        // 40x40 Gram (upper blocks)
  float* out = (float*)d_out;

  // Cooperative fused path requires all 1024 blocks co-resident (4/CU x 256 CU).
  int nb = 0;
  hipError_t qe = hipOccupancyMaxActiveBlocksPerMultiprocessor(
      &nb, (const void*)fused_kernel, 256, 0);
  if (qe == hipSuccess && nb >= 4) {
    void* args[5] = {(void*)&X, (void*)&Yg, (void*)&Pw, (void*)&Mw, (void*)&out};
    hipError_t le = hipLaunchCooperativeKernel((const void*)fused_kernel,
                                               dim3(GB), dim3(256), args, 0, stream);
    if (le == hipSuccess) return;
    (void)hipGetLastError();  // clear error state, fall through
  }

  // fallback: proven 3-kernel path (bit-identical results)
  hipLaunchKernelGGL(gram_kernel,   dim3(GB),  dim3(256), 0, stream, X, Yg, Pw);
  hipLaunchKernelGGL(reduce_kernel, dim3(960), dim3(256), 0, stream, Pw, Mw);
  hipLaunchKernelGGL(solve_kernel,  dim3(1),   dim3(256), 0, stream, Mw, out);
}